// Round 1
// baseline (525.185 us; speedup 1.0000x reference)
//
#include <hip/hip_runtime.h>

#define B 4
#define L 4096
#define D 4096
#define R 32

// ---------------------------------------------------------------------------
// Bulk copy: hidden_states -> out, float4 grid-stride. Memory-bound; this is
// ~all of the kernel's runtime (512 MiB traffic @ ~6.3 TB/s ≈ 85 us).
// ---------------------------------------------------------------------------
__global__ __launch_bounds__(256) void copy_k(const float4* __restrict__ in,
                                              float4* __restrict__ out, int n4) {
    int i = blockIdx.x * blockDim.x + threadIdx.x;
    int stride = gridDim.x * blockDim.x;
    for (; i < n4; i += stride) out[i] = in[i];
}

// ---------------------------------------------------------------------------
// Edit kernel: one block per edited row (B*8 = 32 blocks, 256 threads).
// Row edit: t = relu(x.Wsrc^T + b) - x.Wproj^T ; out_row = x + t.Wproj
// ---------------------------------------------------------------------------
__global__ __launch_bounds__(256) void edit_k(
    const float* __restrict__ hs,
    const float* __restrict__ Wsrc_p, const float* __restrict__ bsrc_p,
    const float* __restrict__ Wproj_p,
    const float* __restrict__ Wsrc_s, const float* __restrict__ bsrc_s,
    const float* __restrict__ Wproj_s,
    const int* __restrict__ offsets, const int* __restrict__ seqlens,
    float* __restrict__ out)
{
    __shared__ float x_lds[D];     // 16 KiB: the row being edited
    __shared__ float t_lds[R];     // rank-32 coefficients

    const int blk = blockIdx.x;    // 0..31
    const int b   = blk >> 3;      // batch
    const int j   = blk & 7;       // 0..3 prefix, 4..7 suffix

    int pos;
    const float *Wsrc, *bsrc, *Wproj;
    if (j < 4) {
        pos   = offsets[b] + j;                      // prefix: off + [0..3]
        Wsrc  = Wsrc_p;  bsrc = bsrc_p;  Wproj = Wproj_p;
    } else {
        pos   = offsets[b] + seqlens[b] + (j - 8);   // suffix: off+len + [-4..-1]
        Wsrc  = Wsrc_s;  bsrc = bsrc_s;  Wproj = Wproj_s;
    }

    const float* x = hs + ((size_t)b * L + pos) * D;
    const int tid = threadIdx.x;

    // Stage x into LDS (coalesced float4).
    for (int i = tid; i < D / 4; i += 256)
        reinterpret_cast<float4*>(x_lds)[i] =
            reinterpret_cast<const float4*>(x)[i];
    __syncthreads();

    // 4 waves; each wave computes 8 of the 32 (src,proj) dot-product pairs.
    const int wave = tid >> 6, lane = tid & 63;
    for (int rr = 0; rr < 8; ++rr) {
        const int r = wave * 8 + rr;
        const float* ws = Wsrc  + (size_t)r * D;
        const float* wp = Wproj + (size_t)r * D;
        float ssum = 0.f, psum = 0.f;
        for (int d = lane * 4; d < D; d += 64 * 4) {
            float4 xv = *reinterpret_cast<const float4*>(&x_lds[d]);
            float4 sv = *reinterpret_cast<const float4*>(&ws[d]);
            float4 pv = *reinterpret_cast<const float4*>(&wp[d]);
            ssum += xv.x * sv.x + xv.y * sv.y + xv.z * sv.z + xv.w * sv.w;
            psum += xv.x * pv.x + xv.y * pv.y + xv.z * pv.z + xv.w * pv.w;
        }
        // 64-lane butterfly reduction.
        #pragma unroll
        for (int off = 32; off >= 1; off >>= 1) {
            ssum += __shfl_xor(ssum, off, 64);
            psum += __shfl_xor(psum, off, 64);
        }
        if (lane == 0) {
            float s = ssum + bsrc[r];
            s = s > 0.f ? s : 0.f;                   // relu
            t_lds[r] = s - psum;
        }
    }
    __syncthreads();

    // out_row = x + sum_r t[r] * Wproj[r][:]   (float4 stores, coalesced)
    float* orow = out + ((size_t)b * L + pos) * D;
    for (int d4 = tid; d4 < D / 4; d4 += 256) {
        float4 acc = reinterpret_cast<const float4*>(x_lds)[d4];
        const int d = d4 * 4;
        #pragma unroll
        for (int r = 0; r < R; ++r) {
            const float t = t_lds[r];
            const float4 wv =
                *reinterpret_cast<const float4*>(&Wproj[(size_t)r * D + d]);
            acc.x += t * wv.x; acc.y += t * wv.y;
            acc.z += t * wv.z; acc.w += t * wv.w;
        }
        reinterpret_cast<float4*>(orow)[d4] = acc;
    }
}

extern "C" void kernel_launch(void* const* d_in, const int* in_sizes, int n_in,
                              void* d_out, int out_size, void* d_ws, size_t ws_size,
                              hipStream_t stream) {
    const float* hs      = (const float*)d_in[0];
    const float* Wsrc_p  = (const float*)d_in[1];
    const float* bsrc_p  = (const float*)d_in[2];
    const float* Wproj_p = (const float*)d_in[3];
    const float* Wsrc_s  = (const float*)d_in[4];
    const float* bsrc_s  = (const float*)d_in[5];
    const float* Wproj_s = (const float*)d_in[6];
    const int*   offsets = (const int*)d_in[7];
    const int*   seqlens = (const int*)d_in[8];
    float*       out     = (float*)d_out;

    const int n4 = (B * L * D) / 4;   // 16,777,216 float4s
    copy_k<<<2048, 256, 0, stream>>>((const float4*)hs, (float4*)out, n4);
    edit_k<<<B * 8, 256, 0, stream>>>(hs, Wsrc_p, bsrc_p, Wproj_p,
                                      Wsrc_s, bsrc_s, Wproj_s,
                                      offsets, seqlens, out);
}